// Round 1
// baseline (1985.348 us; speedup 1.0000x reference)
//
#include <hip/hip_runtime.h>
#include <hip/hip_bf16.h>
#include <stdint.h>

#define DEVINL __device__ __forceinline__

typedef __attribute__((ext_vector_type(8))) short short8;
typedef __attribute__((ext_vector_type(4))) float float4v;

// Problem constants: V=50000, T=32, E=256, HID=512, H=256, L=512, B=64
// Token count M = L*B = 32768. Gates 4H = 1024 per direction, N = 2048 combined.

DEVINL float bf2f(short s) {
  union { unsigned u; float f; } v; v.u = ((unsigned)(unsigned short)s) << 16; return v.f;
}
DEVINL unsigned short f2bf(float f) {
  union { float f; unsigned u; } v; v.f = f;
  unsigned r = v.u + 0x7FFFu + ((v.u >> 16) & 1u);  // RNE
  return (unsigned short)(r >> 16);
}
DEVINL float sigmf(float x) { return __fdividef(1.0f, 1.0f + __expf(-x)); }
DEVINL float tanhf_(float x) {
  x = fminf(20.0f, fmaxf(-20.0f, x));
  float e = __expf(-2.0f * x);
  return __fdividef(1.0f - e, 1.0f + e);
}

// ---------------- K0: f32 -> bf16 converts (8 elems / thread / iter) ----------------
__global__ void k_cvt(const float* __restrict__ src, short* __restrict__ dst, int n8) {
  int i = blockIdx.x * blockDim.x + threadIdx.x;
  int stride = gridDim.x * blockDim.x;
  for (; i < n8; i += stride) {
    const float4v* s = (const float4v*)(src + (size_t)i * 8);
    float4v a = s[0], b = s[1];
    short8 o;
    o[0] = (short)f2bf(a[0]); o[1] = (short)f2bf(a[1]);
    o[2] = (short)f2bf(a[2]); o[3] = (short)f2bf(a[3]);
    o[4] = (short)f2bf(b[0]); o[5] = (short)f2bf(b[1]);
    o[6] = (short)f2bf(b[2]); o[7] = (short)f2bf(b[3]);
    ((short8*)dst)[i] = o;
  }
}

__global__ void k_bias(const float* __restrict__ a1, const float* __restrict__ a2,
                       const float* __restrict__ b1, const float* __restrict__ b2,
                       float* __restrict__ o) {
  int i = blockIdx.x * blockDim.x + threadIdx.x;  // 0..2047
  o[i] = (i < 1024) ? (a1[i] + a2[i]) : (b1[i - 1024] + b2[i - 1024]);
}

// ---------------- K1: x_proj = gather(emb)·W_ihᵀ + (b_ih+b_hh), bf16 out ----------------
// Tiles: 128 tokens × 128 gate-rows, K=256 fully LDS-resident, XOR-swizzled.
__launch_bounds__(256)
__global__ void k_xproj(const int* __restrict__ seqs, const short* __restrict__ embT,
                        const short* __restrict__ wihX, const float* __restrict__ biasX,
                        short* __restrict__ xproj) {
  __shared__ short As[128 * 256];
  __shared__ short Bs[128 * 256];
  __shared__ int ids[128];
  const int bm = blockIdx.x >> 4, bn = blockIdx.x & 15;
  const int tid = threadIdx.x;
  if (tid < 128) ids[tid] = seqs[bm * 128 + tid];
  __syncthreads();
#pragma unroll
  for (int i = 0; i < 16; ++i) {  // stage A (gathered embeddings)
    int task = tid + i * 256, row = task >> 5, kc = task & 31;
    short8 v = *(const short8*)(embT + (size_t)ids[row] * 256 + kc * 8);
    *(short8*)((char*)As + row * 512 + ((kc * 16) ^ ((row & 7) << 4))) = v;
  }
#pragma unroll
  for (int i = 0; i < 16; ++i) {  // stage B (W_ih rows)
    int task = tid + i * 256, row = task >> 5, kc = task & 31;
    short8 v = *(const short8*)(wihX + (size_t)(bn * 128 + row) * 256 + kc * 8);
    *(short8*)((char*)Bs + row * 512 + ((kc * 16) ^ ((row & 7) << 4))) = v;
  }
  __syncthreads();
  const int wave = tid >> 6, lane = tid & 63, l15 = lane & 15, l4 = lane >> 4;
  float4v acc[2][8];
#pragma unroll
  for (int m = 0; m < 2; ++m)
#pragma unroll
    for (int n = 0; n < 8; ++n) acc[m][n] = (float4v){0.f, 0.f, 0.f, 0.f};
#pragma unroll
  for (int kt = 0; kt < 8; ++kt) {
    const int kb = kt * 64 + l4 * 16;
    short8 a[2], b[8];
#pragma unroll
    for (int m = 0; m < 2; ++m) {
      int row = (wave * 2 + m) * 16 + l15;
      a[m] = *(short8*)((char*)As + row * 512 + (kb ^ ((row & 7) << 4)));
    }
#pragma unroll
    for (int n = 0; n < 8; ++n) {
      int row = n * 16 + l15;
      b[n] = *(short8*)((char*)Bs + row * 512 + (kb ^ ((row & 7) << 4)));
    }
#pragma unroll
    for (int m = 0; m < 2; ++m)
#pragma unroll
      for (int n = 0; n < 8; ++n)
        acc[m][n] = __builtin_amdgcn_mfma_f32_16x16x32_bf16(a[m], b[n], acc[m][n], 0, 0, 0);
  }
#pragma unroll
  for (int n = 0; n < 8; ++n) {
    int col = bn * 128 + n * 16 + l15;
    float bias = biasX[col];
#pragma unroll
    for (int m = 0; m < 2; ++m) {
      int token = bm * 128 + (wave * 2 + m) * 16 + l4 * 4;
#pragma unroll
      for (int q = 0; q < 4; ++q)
        xproj[(size_t)(token + q) * 2048 + col] = (short)f2bf(acc[m][n][q] + bias);
    }
  }
}

// ---------------- K2: bidirectional LSTM recurrence ----------------
// 32 WGs: wg = dir*16 + bg*8 + rg. Group (dir,bg) = 8 WGs exchanging h (32 batch, 256 hidden).
// W_hh fragments stationary in VGPRs; h exchanged via agent-scope atomics + flag counter.
__launch_bounds__(256, 1)
__global__ void k_lstm(const short* __restrict__ xproj, const short* __restrict__ whhX,
                       const int* __restrict__ masks, short* __restrict__ h_all,
                       unsigned long long* __restrict__ hX, int* __restrict__ flags) {
  const int wg = blockIdx.x;
  const int dir = wg >> 4, bg = (wg >> 3) & 1, rg = wg & 7, grp = wg >> 3;
  const int tid = threadIdx.x, wave = tid >> 6, lane = tid & 63;
  const int sv = wave >> 1, nt = wave & 1;
  const int l15 = lane & 15, l4 = lane >> 4;
  const int bloc = nt * 16 + l15;        // batch within group (0..31)
  const int bglob = bg * 32 + bloc;      // global batch (0..63)
  const int jbase = sv * 16 + l4 * 4;
  const int kout = rg * 32 + jbase;      // hidden index of this lane's 4 units

  short8 wf[4][8];  // stationary W_hh fragments [gate][kt]
#pragma unroll
  for (int g = 0; g < 4; ++g) {
    const short* wrow = whhX + (size_t)(dir * 1024 + g * 256 + rg * 32 + sv * 16 + l15) * 256;
#pragma unroll
    for (int kt = 0; kt < 8; ++kt) wf[g][kt] = *(const short8*)(wrow + kt * 32 + l4 * 8);
  }

  unsigned long long* hXg = hX + (dir * 2 + bg) * 2 * 2048;  // 2 parities × 2048 ull
  const int wIdx = ((kout >> 3) * 32 + bloc) * 2 + ((kout >> 2) & 1);
  int* flg = flags + grp * 512;

  float c[4] = {0.f, 0.f, 0.f, 0.f}, hq[4] = {0.f, 0.f, 0.f, 0.f};

  int tseq = dir ? 511 : 0;
  unsigned long long xp[4];
#pragma unroll
  for (int g = 0; g < 4; ++g)
    xp[g] = *(const unsigned long long*)(xproj + (size_t)(tseq * 64 + bglob) * 2048 + dir * 1024 + g * 256 + kout);
  int mcur = masks[tseq * 64 + bglob];

#pragma unroll 1
  for (int step = 0; step < 512; ++step) {
    tseq = dir ? (511 - step) : step;
    float4v acc[4];
#pragma unroll
    for (int g = 0; g < 4; ++g) {
      float4v a;
#pragma unroll
      for (int q = 0; q < 4; ++q) a[q] = bf2f((short)(unsigned short)(xp[g] >> (16 * q)));
      acc[g] = a;
    }
    // prefetch next step's x_proj + mask (hides HBM latency behind this step)
    int tn = dir ? (510 - step) : (step + 1);
    tn = tn < 0 ? 0 : (tn > 511 ? 511 : tn);
    unsigned long long xpn[4];
#pragma unroll
    for (int g = 0; g < 4; ++g)
      xpn[g] = *(const unsigned long long*)(xproj + (size_t)(tn * 64 + bglob) * 2048 + dir * 1024 + g * 256 + kout);
    int mn = masks[tn * 64 + bglob];

    if (step > 0) {
      while (__hip_atomic_load(&flg[step - 1], __ATOMIC_RELAXED, __HIP_MEMORY_SCOPE_AGENT) < 8)
        __builtin_amdgcn_s_sleep(1);
      __atomic_signal_fence(__ATOMIC_ACQUIRE);
      unsigned long long* src = hXg + ((step - 1) & 1) * 2048;
      unsigned long long bl[8][2];
#pragma unroll
      for (int kt = 0; kt < 8; ++kt) {
        int base = ((kt * 4 + l4) * 32 + bloc) * 2;
        bl[kt][0] = __hip_atomic_load(src + base,     __ATOMIC_RELAXED, __HIP_MEMORY_SCOPE_AGENT);
        bl[kt][1] = __hip_atomic_load(src + base + 1, __ATOMIC_RELAXED, __HIP_MEMORY_SCOPE_AGENT);
      }
#pragma unroll
      for (int kt = 0; kt < 8; ++kt) {
        union { unsigned long long u[2]; short8 v; } uu;
        uu.u[0] = bl[kt][0]; uu.u[1] = bl[kt][1];
#pragma unroll
        for (int g = 0; g < 4; ++g)
          acc[g] = __builtin_amdgcn_mfma_f32_16x16x32_bf16(wf[g][kt], uu.v, acc[g], 0, 0, 0);
      }
    }

    float outq[4];
#pragma unroll
    for (int q = 0; q < 4; ++q) {
      float iv = sigmf(acc[0][q]);
      float fv = sigmf(acc[1][q]);
      float gv = tanhf_(acc[2][q]);
      float ov = sigmf(acc[3][q]);
      float cn = fv * c[q] + iv * gv;
      float hn = ov * tanhf_(cn);
      c[q]  = mcur ? cn : c[q];
      hq[q] = mcur ? hn : hq[q];
      outq[q] = mcur ? hn : 0.f;
    }
    unsigned long long hp =
        (unsigned long long)f2bf(hq[0]) | ((unsigned long long)f2bf(hq[1]) << 16) |
        ((unsigned long long)f2bf(hq[2]) << 32) | ((unsigned long long)f2bf(hq[3]) << 48);
    unsigned long long op =
        (unsigned long long)f2bf(outq[0]) | ((unsigned long long)f2bf(outq[1]) << 16) |
        ((unsigned long long)f2bf(outq[2]) << 32) | ((unsigned long long)f2bf(outq[3]) << 48);
    __hip_atomic_store(hXg + (step & 1) * 2048 + wIdx, hp, __ATOMIC_RELAXED, __HIP_MEMORY_SCOPE_AGENT);
    *(unsigned long long*)(h_all + (size_t)(tseq * 64 + bglob) * 512 + dir * 256 + kout) = op;
    __syncthreads();  // drains all waves' stores (vmcnt(0) before barrier)
    if (tid == 0)
      __hip_atomic_fetch_add(&flg[step], 1, __ATOMIC_RELAXED, __HIP_MEMORY_SCOPE_AGENT);
#pragma unroll
    for (int g = 0; g < 4; ++g) xp[g] = xpn[g];
    mcur = mn;
  }
}

// ---------------- K3: emissions = h_all·W_outᵀ + b_out (f32) ----------------
__launch_bounds__(256)
__global__ void k_emis(const short* __restrict__ h_all, const short* __restrict__ woutX,
                       const float* __restrict__ bout, float* __restrict__ emis) {
  const int tid = threadIdx.x, wave = tid >> 6, lane = tid & 63;
  const int l15 = lane & 15, l4 = lane >> 4;
  const int token0 = blockIdx.x * 256 + wave * 64;
  float4v acc[4][2];
#pragma unroll
  for (int m = 0; m < 4; ++m)
#pragma unroll
    for (int n = 0; n < 2; ++n) acc[m][n] = (float4v){0.f, 0.f, 0.f, 0.f};
#pragma unroll
  for (int kt = 0; kt < 16; ++kt) {
    short8 b[2];
#pragma unroll
    for (int n = 0; n < 2; ++n)
      b[n] = *(const short8*)(woutX + (size_t)(n * 16 + l15) * 512 + kt * 32 + l4 * 8);
#pragma unroll
    for (int m = 0; m < 4; ++m) {
      short8 a = *(const short8*)(h_all + (size_t)(token0 + m * 16 + l15) * 512 + kt * 32 + l4 * 8);
#pragma unroll
      for (int n = 0; n < 2; ++n)
        acc[m][n] = __builtin_amdgcn_mfma_f32_16x16x32_bf16(a, b[n], acc[m][n], 0, 0, 0);
    }
  }
#pragma unroll
  for (int n = 0; n < 2; ++n) {
    float bias = bout[n * 16 + l15];
#pragma unroll
    for (int m = 0; m < 4; ++m) {
      int token = token0 + m * 16 + l4 * 4;
#pragma unroll
      for (int q = 0; q < 4; ++q)
        emis[(size_t)(token + q) * 32 + n * 16 + l15] = acc[m][n][q] + bias;
    }
  }
}

// ---------------- K4: CRF numerator + partition scan + final reduce ----------------
__launch_bounds__(64)
__global__ void k_crf(const float* __restrict__ emis, const int* __restrict__ tags,
                      const int* __restrict__ masks, const float* __restrict__ strans,
                      const float* __restrict__ etrans, const float* __restrict__ trans,
                      float* __restrict__ out) {
  __shared__ float trans_s[1024];
  __shared__ float score_s[32];
  const int b = blockIdx.x, lane = threadIdx.x;
  for (int i = lane; i < 1024; i += 64) trans_s[i] = trans[i];

  // numerator (t-parallel across the wave)
  float num = 0.f; int lensum = 0;
#pragma unroll 1
  for (int i = 0; i < 8; ++i) {
    int t = lane + i * 64;
    int tg = tags[t * 64 + b];
    int m = masks[t * 64 + b];
    lensum += m;
    float e = emis[(size_t)(t * 64 + b) * 32 + tg];
    if (t == 0) num += strans[tg] + e;
    else if (m) num += e + trans[tags[(t - 1) * 64 + b] * 32 + tg];
  }
#pragma unroll
  for (int o = 32; o > 0; o >>= 1) { num += __shfl_down(num, o); lensum += __shfl_down(lensum, o); }
  num = __shfl(num, 0);
  lensum = __shfl(lensum, 0);
  num += etrans[tags[(lensum - 1) * 64 + b]];
  __syncthreads();

  const int jp = lane & 31, half = lane >> 5;
  if (lane < 32) score_s[jp] = strans[jp] + emis[(size_t)b * 32 + jp];
  __syncthreads();

  float e_next = emis[(size_t)(64 + b) * 32 + jp];
#pragma unroll 1
  for (int t = 1; t < 512; ++t) {
    float e = e_next;
    if (t < 511) e_next = emis[(size_t)((t + 1) * 64 + b) * 32 + jp];
    int m = masks[t * 64 + b];
    float v[16], mx = -1e30f;
#pragma unroll
    for (int j = 0; j < 16; ++j) {
      v[j] = score_s[half * 16 + j] + trans_s[(half * 16 + j) * 32 + jp];
      mx = fmaxf(mx, v[j]);
    }
    float sum = 0.f;
#pragma unroll
    for (int j = 0; j < 16; ++j) sum += __expf(v[j] - mx);
    float mo = __shfl_xor(mx, 32), so = __shfl_xor(sum, 32);
    float mn2 = fmaxf(mx, mo);
    sum = sum * __expf(mx - mn2) + so * __expf(mo - mn2);
    float nxt = e + mn2 + __logf(sum);
    float cur = score_s[jp];
    float ns = m ? nxt : cur;
    __syncthreads();
    if (lane < 32) score_s[jp] = ns;
    __syncthreads();
  }

  float vv = (lane < 32) ? (score_s[jp] + etrans[jp]) : -1e30f;
  float mx = vv;
#pragma unroll
  for (int o = 32; o > 0; o >>= 1) mx = fmaxf(mx, __shfl_xor(mx, o));
  float sm = (lane < 32) ? __expf(vv - mx) : 0.f;
#pragma unroll
  for (int o = 32; o > 0; o >>= 1) sm += __shfl_xor(sm, o);
  float lz = mx + __logf(sm);
  if (lane == 0) atomicAdd(out, -(num - lz) * (1.0f / 64.0f));
}

// ---------------- launch ----------------
extern "C" void kernel_launch(void* const* d_in, const int* in_sizes, int n_in,
                              void* d_out, int out_size, void* d_ws, size_t ws_size,
                              hipStream_t stream) {
  const int*   seqs  = (const int*)d_in[0];
  const int*   tags  = (const int*)d_in[1];
  const int*   masks = (const int*)d_in[2];
  const float* embed = (const float*)d_in[3];
  const float* Wihf  = (const float*)d_in[4];
  const float* Whhf  = (const float*)d_in[5];
  const float* bihf  = (const float*)d_in[6];
  const float* bhhf  = (const float*)d_in[7];
  const float* Wihb  = (const float*)d_in[8];
  const float* Whhb  = (const float*)d_in[9];
  const float* bihb  = (const float*)d_in[10];
  const float* bhhb  = (const float*)d_in[11];
  const float* Wout  = (const float*)d_in[12];
  const float* bout  = (const float*)d_in[13];
  const float* strn  = (const float*)d_in[14];
  const float* etrn  = (const float*)d_in[15];
  const float* trn   = (const float*)d_in[16];
  float* outf = (float*)d_out;

  char* ws = (char*)d_ws;
  short* xproj = (short*)(ws + 0);             // 134,217,728 B
  short* h_all = (short*)(ws + 134217728);     //  33,554,432 B
  float* emis  = (float*)(ws + 167772160);     //   4,194,304 B
  short* embT  = (short*)(ws + 171966464);     //  25,600,000 B
  short* wihX  = (short*)(ws + 197566464);     //   1,048,576 B
  short* whhX  = (short*)(ws + 198615040);     //   1,048,576 B
  short* woutX = (short*)(ws + 199663616);     //      32,768 B
  float* biasX = (float*)(ws + 199696384);     //       8,192 B
  unsigned long long* hX = (unsigned long long*)(ws + 199704576);  // 131,072 B
  int* flags = (int*)(ws + 199835648);         //       8,192 B

  hipMemsetAsync(flags, 0, 8192, stream);
  hipMemsetAsync(d_out, 0, 4, stream);

  k_cvt<<<2048, 256, 0, stream>>>(embed, embT, 1600000);
  k_cvt<<<128, 256, 0, stream>>>(Wihf, wihX, 32768);
  k_cvt<<<128, 256, 0, stream>>>(Wihb, wihX + 262144, 32768);
  k_cvt<<<128, 256, 0, stream>>>(Whhf, whhX, 32768);
  k_cvt<<<128, 256, 0, stream>>>(Whhb, whhX + 262144, 32768);
  k_cvt<<<8, 256, 0, stream>>>(Wout, woutX, 2048);
  k_bias<<<2, 1024, 0, stream>>>(bihf, bhhf, bihb, bhhb, biasX);
  k_xproj<<<4096, 256, 0, stream>>>(seqs, embT, wihX, biasX, xproj);
  k_lstm<<<32, 256, 0, stream>>>(xproj, whhX, masks, h_all, hX, flags);
  k_emis<<<128, 256, 0, stream>>>(h_all, woutX, bout, emis);
  k_crf<<<64, 64, 0, stream>>>(emis, tags, masks, strn, etrn, trn, outf);
}